// Round 2
// baseline (1354.539 us; speedup 1.0000x reference)
//
#include <hip/hip_runtime.h>
#include <cstdint>
#include <cstddef>

#define NB 4
#define NN 1000
#define NPAD 1024
#define HW 65536          // 256*256 pixels per mask
#define MAXDET 100
#define MIN_SIZE 25.0f
#define IOU_T 0.3f
#define PARTS 8           // blocks per mask copy
#define PART_F4 (HW / 4 / PARTS)   // 2048 float4 per part

// Flat output layout (floats), concatenated in reference return order:
// boxes [4,100,4], masks [4,100,1,256,256], scores [4,100], labels [4,100], valid [4,100]
#define OFF_BOXES  0
#define OFF_MASKS  (NB * MAXDET * 4)
#define OFF_SCORES (OFF_MASKS + (size_t)NB * MAXDET * HW)
#define OFF_LABELS (OFF_SCORES + NB * MAXDET)
#define OFF_VALID  (OFF_LABELS + NB * MAXDET)

typedef float f4_ev __attribute__((ext_vector_type(4)));

__global__ __launch_bounds__(1024) void nms_all(
    const float* __restrict__ boxes,    // [B,N,4]
    const float* __restrict__ scores,   // [B,N]
    const int*   __restrict__ labels,   // [B,N]
    float* __restrict__ out,            // flat output buffer
    int*   __restrict__ sel)            // [B*MAXDET]
{
    // Suppression matrix lives entirely in LDS: row i (sorted), word w covers
    // sorted cols w*64..w*64+63.  1000*16*8 = 125 KB.
    __shared__ unsigned long long s_gmask[NN * 16];
    __shared__ float  s_score[NPAD];    // sort exchange buffer (j>=64 passes)
    __shared__ int    s_idx[NPAD];
    __shared__ float4 s_box[NPAD];
    __shared__ float  s_area[NPAD];
    __shared__ unsigned long long s_validbits[16];
    __shared__ unsigned long long s_sup[16];
    __shared__ int    s_wsum[16];
    __shared__ int    s_woff[17];
    // total static LDS = 128000 + 29060 = 157060 B  (<= 160 KiB/CU, 1 wg/CU)

    const int b    = blockIdx.x;
    const int tid  = threadIdx.x;
    const int wv   = tid >> 6;          // wave id 0..15
    const int lane = tid & 63;

    const float4* bb4 = (const float4*)(boxes + (size_t)b * NN * 4);
    const float*  bsc = scores + (size_t)b * NN;
    const int*    blb = labels + (size_t)b * NN;

    // ---- phase 1: masked score + identity idx in REGISTERS; zero LDS mask ----
    float sc = -INFINITY;
    int   id = tid;
    if (tid < NN) {
        float4 v = bb4[tid];
        float a = (v.z - v.x) * (v.w - v.y);
        if (a > MIN_SIZE) sc = bsc[tid];
    }
    for (int t = tid; t < NN * 16; t += 1024) s_gmask[t] = 0ull;

    // ---- phase 2: hybrid bitonic sort, descending score, tie ascending idx ----
    // j >= 64  -> LDS exchange (10 passes, 2 barriers each)
    // j <  64  -> in-wave register exchange via shfl_xor (45 passes, 0 barriers)
    for (int k = 2; k <= NPAD; k <<= 1) {
        const bool up = ((tid & k) == 0);     // pair-uniform (j < k)
        for (int j = k >> 1; j > 0; j >>= 1) {
            float so; int io;
            if (j >= 64) {
                s_score[tid] = sc; s_idx[tid] = id;
                __syncthreads();
                int p = tid ^ j;
                so = s_score[p]; io = s_idx[p];
                __syncthreads();              // reads done before next write
            } else {
                so = __shfl_xor(sc, j);
                io = __shfl_xor(id, j);
            }
            bool a_first = (sc > so) || (sc == so && id < io);
            bool lower = (tid & j) == 0;
            bool keep_first = (up == lower);
            if (keep_first != a_first) { sc = so; id = io; }
        }
    }
    // registers (sc,id) now hold the fully sorted sequence at position tid

    // ---- phase 3: gather sorted boxes (SoA), validity ballot ----
    {
        float4 bx = make_float4(0.f, 0.f, 0.f, 0.f);
        float ar = 0.f;
        bool val = false;
        if (id < NN) {
            bx = bb4[id];
            ar = (bx.z - bx.x) * (bx.w - bx.y);
            val = ar > MIN_SIZE;
        }
        s_box[tid] = bx;
        s_area[tid] = ar;
        unsigned long long vb = __ballot(val);
        if (lane == 0) s_validbits[wv] = vb;
    }
    __syncthreads();

    // ---- phase 4: suppression bitmask build (upper triangle, balanced) ----
    // pair p -> (rb, w), rb<=w<16; row i = rb*64+lane; word w covers cols w*64..+63
    for (int p = wv; p < 136; p += 16) {
        int rb = 0, base = 0;
        while (base + 16 - rb <= p) { base += 16 - rb; ++rb; }
        int w = rb + (p - base);
        int i = (rb << 6) + lane;
        float4 bi = s_box[i];
        float  ai = s_area[i];
        unsigned long long m = 0ull;
        int jb = w << 6;
        for (int j2 = 0; j2 < 64; ++j2) {
            int j = jb + j2;
            float4 bj = s_box[j];          // same addr across wave -> broadcast
            float  aj = s_area[j];
            float ltx = fmaxf(bi.x, bj.x);
            float lty = fmaxf(bi.y, bj.y);
            float rbx = fminf(bi.z, bj.z);
            float rby = fminf(bi.w, bj.w);
            float cw = fmaxf(rbx - ltx, 0.0f);
            float ch = fmaxf(rby - lty, 0.0f);
            float inter = cw * ch;
            float den = ai + aj - inter;
            float iou = (den > 0.0f) ? (inter / den) : 0.0f;  // exact ref arithmetic
            m |= (unsigned long long)((iou > IOU_T) && (j > i)) << j2;
        }
        if (i < NN) s_gmask[i * 16 + w] = m;
    }
    __syncthreads();   // s_gmask visible block-wide

    // ---- phase 5: greedy walk, single wave, ffs-skip + 2-deep speculative ----
    // cand = valid & ~suppressed (wave-uniform). Speculatively issue the LDS
    // load for the NEXT candidate row before consuming the current one; the
    // speculation only fails when the current row suppresses the next
    // candidate (~1-2% of pairs), in which case we re-issue.
    if (tid < 64) {
        const int wsel = lane & 15;      // word owned (replicated x4 groups)
        unsigned long long sup = 0ull;
        for (int c = 0; c < 16; ++c) {
            unsigned long long supw = __shfl(sup, c);    // uniform c -> readlane
            unsigned long long vw = s_validbits[c];
            unsigned long long cm = (c == 15)
                ? ((1ull << (NN - 15 * 64)) - 1ull)      // only 40 rows in last chunk
                : ~0ull;
            unsigned long long cand = vw & ~supw & cm;
            int bit = -1;
            unsigned long long pref = 0ull;
            if (cand) {
                bit = __builtin_ctzll(cand);
                pref = s_gmask[(((c << 6) + bit) << 4) + wsel];
            }
            while (bit >= 0) {
                unsigned long long cand2 = cand & ~(1ull << bit);
                int nbit = -1;
                unsigned long long npref = 0ull;
                if (cand2) {                              // speculative prefetch
                    nbit = __builtin_ctzll(cand2);
                    npref = s_gmask[(((c << 6) + nbit) << 4) + wsel];
                }
                sup |= pref;                              // consume current row
                supw = __shfl(sup, c);
                cand = cand2 & ~supw;
                if (nbit >= 0 && ((cand >> nbit) & 1ull) == 0ull) {
                    // speculation miss: next candidate got suppressed
                    if (cand) {
                        nbit = __builtin_ctzll(cand);
                        npref = s_gmask[(((c << 6) + nbit) << 4) + wsel];
                    } else {
                        nbit = -1; npref = 0ull;
                    }
                }
                bit = nbit; pref = npref;
            }
        }
        if (lane < 16) s_sup[lane] = sup;
    }
    __syncthreads();

    // ---- phase 6: compaction via ballot-scan, write small outputs ----
    unsigned long long vwd = s_validbits[wv];
    unsigned long long swd = s_sup[wv];
    bool kp = (((vwd >> lane) & 1ull) != 0) && (((swd >> lane) & 1ull) == 0);
    unsigned long long bal = __ballot(kp);
    int lprefix = __popcll(bal & ((1ull << lane) - 1ull));
    if (lane == 0) s_wsum[wv] = __popcll(bal);
    __syncthreads();
    if (tid == 0) {
        int s = 0;
        for (int q = 0; q < 16; ++q) { s_woff[q] = s; s += s_wsum[q]; }
        s_woff[16] = s;
    }
    __syncthreads();
    int rank  = s_woff[wv] + lprefix;
    int total = s_woff[16];

    float* out_boxes  = out + OFF_BOXES;
    float* out_scores = out + OFF_SCORES;
    float* out_labels = out + OFF_LABELS;
    float* out_valid  = out + OFF_VALID;
    const int slot_base = b * MAXDET;

    if (kp && rank < MAXDET) {
        int slot = slot_base + rank;
        sel[slot] = id;                              // sorted original index
        ((float4*)out_boxes)[slot] = s_box[tid];     // == boxes[id]
        out_scores[slot] = sc;                       // == scores[id] (valid)
        out_labels[slot] = (float)blb[id];
        out_valid[slot]  = 1.0f;
    }
    int count = total < MAXDET ? total : MAXDET;
    if (tid >= count && tid < MAXDET) {
        int slot = slot_base + tid;
        sel[slot] = -1;
        ((float4*)out_boxes)[slot] = make_float4(0.f, 0.f, 0.f, 0.f);
        out_scores[slot] = 0.0f;
        out_labels[slot] = -1.0f;
        out_valid[slot]  = 0.0f;
    }
}

__global__ __launch_bounds__(256) void gather_masks(
    const float* __restrict__ masks,    // [B,N,1,256,256]
    const int*   __restrict__ sel,      // [B*MAXDET]
    float* __restrict__ out_masks)      // [B,MAXDET,1,256,256]
{
    int blk  = blockIdx.x;
    int slot = blk / PARTS;
    int part = blk % PARTS;
    int b    = slot / MAXDET;
    int fi   = sel[slot];

    f4_ev* dst = (f4_ev*)out_masks + (size_t)slot * (HW / 4) + (size_t)part * PART_F4;
    if (fi >= 0) {
        const f4_ev* src = (const f4_ev*)masks
                         + (size_t)(b * NN + fi) * (HW / 4) + (size_t)part * PART_F4;
        for (int t = threadIdx.x; t < PART_F4; t += 256) {
            f4_ev v = __builtin_nontemporal_load(&src[t]);   // streaming, no reuse
            __builtin_nontemporal_store(v, &dst[t]);
        }
    } else {
        f4_ev z = (f4_ev){0.f, 0.f, 0.f, 0.f};
        for (int t = threadIdx.x; t < PART_F4; t += 256)
            __builtin_nontemporal_store(z, &dst[t]);
    }
}

extern "C" void kernel_launch(void* const* d_in, const int* in_sizes, int n_in,
                              void* d_out, int out_size, void* d_ws, size_t ws_size,
                              hipStream_t stream) {
    const float* boxes  = (const float*)d_in[0];
    const float* masks  = (const float*)d_in[1];
    const float* scores = (const float*)d_in[2];
    const int*   labels = (const int*)d_in[3];
    float* out = (float*)d_out;
    int*   sel = (int*)d_ws;

    nms_all<<<NB, 1024, 0, stream>>>(boxes, scores, labels, out, sel);
    gather_masks<<<NB * MAXDET * PARTS, 256, 0, stream>>>(masks, sel, out + OFF_MASKS);
}